// Round 1
// baseline (323.232 us; speedup 1.0000x reference)
//
#include <hip/hip_runtime.h>
#include <hip/hip_bf16.h>

// B=4, S=2048, D_MODEL=1024, H=16, HD=32, SCALE=8.0
typedef unsigned short u16;
typedef __attribute__((ext_vector_type(8))) short s16x8;
typedef __attribute__((ext_vector_type(4))) short s16x4;
typedef __attribute__((ext_vector_type(4))) float f32x4;

#define DEV static __device__ __forceinline__

DEV u16 f2bf(float f){
  __hip_bfloat16 h = __float2bfloat16(f);
  return *reinterpret_cast<u16*>(&h);
}

// ---------------- mask dtype detect + bit-pack ----------------
__global__ void detect_mask_kernel(const unsigned char* __restrict__ m, int* __restrict__ flag){
  __shared__ int cnt;
  if (threadIdx.x==0) cnt=0;
  __syncthreads();
  int nz=0;
  for (int i=threadIdx.x;i<4096;i+=256) nz += (m[(size_t)i*4+1]!=0)?1:0;
  if (nz) atomicAdd(&cnt, nz);
  __syncthreads();
  if (threadIdx.x==0) *flag = (cnt==0)?4:1;   // 4: int32 mask (read LSB), 1: bool/uint8
}

__global__ __launch_bounds__(256) void pack_mask_kernel(const unsigned char* __restrict__ m,
    const int* __restrict__ flag, unsigned long long* __restrict__ mb){
  const int stride = *flag;
  const size_t gid = (size_t)blockIdx.x*256u + threadIdx.x;
  const unsigned char v = m[gid*(size_t)stride];
  unsigned long long bal = __ballot(v != 0);
  if ((threadIdx.x&63u)==0u) mb[gid>>6] = bal;
}

// ---------------- weight prep: bf16 + [n][k] transpose ----------------
// WT: [3][512][1024]  (n = h*32+e, k = d)   WoT: [1024][512] (n = dmodel, k = h*32+e)
__global__ __launch_bounds__(256) void prep_weights_kernel(
    const float* __restrict__ Wq, const float* __restrict__ Wk, const float* __restrict__ Wv,
    const float* __restrict__ Wo, u16* __restrict__ WT, u16* __restrict__ WoT){
  int gid = blockIdx.x*256 + threadIdx.x;
  if (gid < 3*512*1024){
    int z = gid >> 19;
    int r = gid & ((1<<19)-1);
    int n = r >> 10, d = r & 1023;
    const float* W = (z==0)?Wq:((z==1)?Wk:Wv);
    int h = n>>5, e = n&31;
    WT[gid] = f2bf(W[((size_t)h*1024 + (size_t)d)*32 + e]);
  } else {
    int r = gid - 3*512*1024;
    int n = r >> 9, cc = r & 511;
    WoT[r] = f2bf(Wo[(size_t)cc*1024 + n]);
  }
}

// ---------------- projection GEMM: [8192x1024]f32 x WT[n][k] -> Q/K (bf16 [B,H,S,32]) or V^T (bf16 [B,H,32,S])
__global__ __launch_bounds__(256) void gemm_proj_kernel(
    const float* __restrict__ Aq, const float* __restrict__ Ak, const float* __restrict__ Av,
    const u16* __restrict__ WT, u16* __restrict__ Qp, u16* __restrict__ Kp, u16* __restrict__ Vt)
{
  __shared__ u16 As[128*64];
  __shared__ u16 Bs[128*64];
  const int z = blockIdx.z;
  const float* __restrict__ A = (z==0)?Aq:((z==1)?Ak:Av);
  const u16* __restrict__ W = WT + (size_t)z*(512*1024);
  const int m0 = blockIdx.x*128, n0 = blockIdx.y*128;
  const int t = threadIdx.x, lane = t&63, wv = t>>6;
  const int wr = wv>>1, wc = wv&1;
  const int c = lane&15, g = lane>>4;
  f32x4 acc[4][4] = {};
  for (int kk=0; kk<1024; kk+=64){
    #pragma unroll
    for (int j=0;j<8;j++){                       // A: 128x64 f32 -> bf16 LDS (swizzled)
      int idx = t + j*256;
      int row = idx>>4, kq=(idx&15)<<2;
      f32x4 a4 = *(const f32x4*)(A + (size_t)(m0+row)*1024 + kk + kq);
      s16x4 b4;
      b4[0]=(short)f2bf(a4[0]); b4[1]=(short)f2bf(a4[1]);
      b4[2]=(short)f2bf(a4[2]); b4[3]=(short)f2bf(a4[3]);
      int co = (kq<<1) ^ ((row&7)<<4);
      *(s16x4*)((char*)As + row*128 + co) = b4;
    }
    #pragma unroll
    for (int j=0;j<4;j++){                       // B: 128x64 bf16
      int idx = t + j*256;
      int n = idx>>3, k8=(idx&7)<<3;
      s16x8 bv = *(const s16x8*)(W + (size_t)(n0+n)*1024 + kk + k8);
      int co = (k8<<1) ^ ((n&7)<<4);
      *(s16x8*)((char*)Bs + n*128 + co) = bv;
    }
    __syncthreads();
    #pragma unroll
    for (int ks=0;ks<2;ks++){
      s16x8 af[4], bf[4];
      #pragma unroll
      for (int i=0;i<4;i++){
        int ra = wr*64 + i*16 + c;
        af[i] = *(const s16x8*)((const char*)As + ra*128 + ((ks*64 + g*16) ^ ((ra&7)<<4)));
        int rb = wc*64 + i*16 + c;
        bf[i] = *(const s16x8*)((const char*)Bs + rb*128 + ((ks*64 + g*16) ^ ((rb&7)<<4)));
      }
      #pragma unroll
      for (int mi=0;mi<4;mi++)
        #pragma unroll
        for (int nj=0;nj<4;nj++)
          acc[mi][nj] = __builtin_amdgcn_mfma_f32_16x16x32_bf16(af[mi], bf[nj], acc[mi][nj], 0, 0, 0);
    }
    __syncthreads();
  }
  #pragma unroll
  for (int mi=0;mi<4;mi++){
    #pragma unroll
    for (int nj=0;nj<4;nj++){
      #pragma unroll
      for (int r=0;r<4;r++){
        int gm = m0 + wr*64 + mi*16 + g*4 + r;
        int gn = n0 + wc*64 + nj*16 + c;
        u16 val = f2bf(acc[mi][nj][r]);
        int b = gm>>11, s = gm&2047, hh = gn>>5, e = gn&31;
        if (z==0)      Qp[((size_t)(b*16+hh)*2048 + s)*32 + e] = val;
        else if (z==1) Kp[((size_t)(b*16+hh)*2048 + s)*32 + e] = val;
        else           Vt[((size_t)(b*16+hh)*32 + e)*2048 + s] = val;
      }
    }
  }
}

// ---------------- flash attention: per (qtile, b*h); 4 waves x 16 q-rows; KBLK=64 ----------------
__global__ __launch_bounds__(256) void attn_kernel(
    const u16* __restrict__ Qp, const u16* __restrict__ Kp, const u16* __restrict__ Vt,
    const unsigned long long* __restrict__ mb, u16* __restrict__ Z)
{
  __shared__ u16 P[4][16][72];                  // per-wave P slab, 144B row stride (bank-friendly)
  const int t = threadIdx.x, lane = t&63, w = t>>6;
  const int c = lane&15, g = lane>>4;
  const int bh = blockIdx.y, b = bh>>4, h = bh&15;
  const int q0w = blockIdx.x*64 + w*16;
  const u16* Qh = Qp + (size_t)bh*2048*32;
  const u16* Kh = Kp + (size_t)bh*2048*32;
  const u16* Vh = Vt + (size_t)bh*32*2048;
  const f32x4 z4 = {0.f,0.f,0.f,0.f};
  const s16x8 qf = *(const s16x8*)(Qh + (size_t)(q0w + c)*32 + g*8);
  f32x4 O0 = z4, O1 = z4;
  float mrun[4] = {-INFINITY,-INFINITY,-INFINITY,-INFINITY};
  float lrun[4] = {0.f,0.f,0.f,0.f};
  const size_t mrowbase = ((size_t)b*2048 + (size_t)(q0w + g*4)) * 32;  // uint64 words per row = 32

  for (int kb=0; kb<2048; kb+=64){
    s16x8 kf[4];
    #pragma unroll
    for (int t4=0;t4<4;t4++)
      kf[t4] = *(const s16x8*)(Kh + (size_t)(kb + t4*16 + c)*32 + g*8);
    s16x8 v00 = *(const s16x8*)(Vh + (size_t)c*2048      + kb      + g*8);
    s16x8 v10 = *(const s16x8*)(Vh + (size_t)c*2048      + kb + 32 + g*8);
    s16x8 v01 = *(const s16x8*)(Vh + (size_t)(16+c)*2048 + kb      + g*8);
    s16x8 v11 = *(const s16x8*)(Vh + (size_t)(16+c)*2048 + kb + 32 + g*8);

    f32x4 sc[4];
    #pragma unroll
    for (int t4=0;t4<4;t4++)
      sc[t4] = __builtin_amdgcn_mfma_f32_16x16x32_bf16(qf, kf[t4], z4, 0, 0, 0);

    const int kw = kb>>6;
    unsigned long long mw[4];
    #pragma unroll
    for (int r=0;r<4;r++) mw[r] = mb[mrowbase + (size_t)r*32 + kw];

    #pragma unroll
    for (int t4=0;t4<4;t4++){
      #pragma unroll
      for (int r=0;r<4;r++){
        float x = sc[t4][r]*0.125f;              // / sqrt(64)
        if ((mw[r] >> (t4*16 + c)) & 1ull) x = -1e10f;
        sc[t4][r] = x;
      }
    }
    float mx[4];
    #pragma unroll
    for (int r=0;r<4;r++) mx[r] = fmaxf(fmaxf(sc[0][r],sc[1][r]),fmaxf(sc[2][r],sc[3][r]));
    #pragma unroll
    for (int d=1; d<16; d<<=1){
      #pragma unroll
      for (int r=0;r<4;r++) mx[r] = fmaxf(mx[r], __shfl_xor(mx[r], d));
    }
    float fr[4], rs[4];
    #pragma unroll
    for (int r=0;r<4;r++){
      float nm = fmaxf(mrun[r], mx[r]);
      fr[r] = __expf(mrun[r] - nm);
      mrun[r] = nm;
    }
    #pragma unroll
    for (int t4=0;t4<4;t4++)
      #pragma unroll
      for (int r=0;r<4;r++) sc[t4][r] = __expf(sc[t4][r] - mrun[r]);
    #pragma unroll
    for (int r=0;r<4;r++) rs[r] = (sc[0][r]+sc[1][r])+(sc[2][r]+sc[3][r]);
    #pragma unroll
    for (int d=1; d<16; d<<=1){
      #pragma unroll
      for (int r=0;r<4;r++) rs[r] += __shfl_xor(rs[r], d);
    }
    #pragma unroll
    for (int r=0;r<4;r++){
      lrun[r] = lrun[r]*fr[r] + rs[r];
      O0[r] *= fr[r];
      O1[r] *= fr[r];
    }
    // P (C-layout) -> LDS -> A-operand layout; wave-private region, no barrier needed
    #pragma unroll
    for (int t4=0;t4<4;t4++)
      #pragma unroll
      for (int r=0;r<4;r++) P[w][g*4+r][t4*16+c] = f2bf(sc[t4][r]);
    s16x8 pf0 = *(const s16x8*)(&P[w][c][g*8]);
    s16x8 pf1 = *(const s16x8*)(&P[w][c][32 + g*8]);
    O0 = __builtin_amdgcn_mfma_f32_16x16x32_bf16(pf0, v00, O0, 0,0,0);
    O0 = __builtin_amdgcn_mfma_f32_16x16x32_bf16(pf1, v10, O0, 0,0,0);
    O1 = __builtin_amdgcn_mfma_f32_16x16x32_bf16(pf0, v01, O1, 0,0,0);
    O1 = __builtin_amdgcn_mfma_f32_16x16x32_bf16(pf1, v11, O1, 0,0,0);
  }
  #pragma unroll
  for (int r=0;r<4;r++){
    float inv = 1.f/lrun[r];
    size_t zb = ((size_t)b*2048 + (size_t)(q0w + g*4 + r))*512 + h*32;
    Z[zb + c]      = f2bf(O0[r]*inv);
    Z[zb + 16 + c] = f2bf(O1[r]*inv);
  }
}

// ---------------- output GEMM: Z[8192x512]bf16 x WoT[1024][512] -> out f32 ----------------
__global__ __launch_bounds__(256) void gemm_out_kernel(
    const u16* __restrict__ Zb, const u16* __restrict__ WoT, float* __restrict__ out)
{
  __shared__ u16 As[128*64];
  __shared__ u16 Bs[128*64];
  const int m0 = blockIdx.x*128, n0 = blockIdx.y*128;
  const int t = threadIdx.x, lane=t&63, wv=t>>6;
  const int wr=wv>>1, wc=wv&1, c=lane&15, g=lane>>4;
  f32x4 acc[4][4] = {};
  for (int kk=0; kk<512; kk+=64){
    #pragma unroll
    for (int j=0;j<4;j++){
      int idx = t + j*256;
      int row = idx>>3, k8=(idx&7)<<3;
      int co = (k8<<1) ^ ((row&7)<<4);
      s16x8 av = *(const s16x8*)(Zb + (size_t)(m0+row)*512 + kk + k8);
      *(s16x8*)((char*)As + row*128 + co) = av;
      s16x8 bv = *(const s16x8*)(WoT + (size_t)(n0+row)*512 + kk + k8);
      *(s16x8*)((char*)Bs + row*128 + co) = bv;
    }
    __syncthreads();
    #pragma unroll
    for (int ks=0;ks<2;ks++){
      s16x8 af[4], bf[4];
      #pragma unroll
      for (int i=0;i<4;i++){
        int ra = wr*64 + i*16 + c;
        af[i] = *(const s16x8*)((const char*)As + ra*128 + ((ks*64 + g*16) ^ ((ra&7)<<4)));
        int rb = wc*64 + i*16 + c;
        bf[i] = *(const s16x8*)((const char*)Bs + rb*128 + ((ks*64 + g*16) ^ ((rb&7)<<4)));
      }
      #pragma unroll
      for (int mi=0;mi<4;mi++)
        #pragma unroll
        for (int nj=0;nj<4;nj++)
          acc[mi][nj] = __builtin_amdgcn_mfma_f32_16x16x32_bf16(af[mi], bf[nj], acc[mi][nj], 0, 0, 0);
    }
    __syncthreads();
  }
  #pragma unroll
  for (int mi=0;mi<4;mi++)
    #pragma unroll
    for (int nj=0;nj<4;nj++)
      #pragma unroll
      for (int r=0;r<4;r++){
        int gm = m0 + wr*64 + mi*16 + g*4 + r;
        int gn = n0 + wc*64 + nj*16 + c;
        out[(size_t)gm*1024 + gn] = acc[mi][nj][r];
      }
}

// ---------------- launcher ----------------
extern "C" void kernel_launch(void* const* d_in, const int* in_sizes, int n_in,
                              void* d_out, int out_size, void* d_ws, size_t ws_size,
                              hipStream_t stream)
{
  const float* q  = (const float*)d_in[0];
  const float* k  = (const float*)d_in[1];
  const float* v  = (const float*)d_in[2];
  const unsigned char* mask = (const unsigned char*)d_in[3];
  const float* Wq = (const float*)d_in[4];
  const float* Wk = (const float*)d_in[5];
  const float* Wv = (const float*)d_in[6];
  const float* Wo = (const float*)d_in[7];
  float* out = (float*)d_out;

  char* ws = (char*)d_ws;
  // workspace map (total ~38 MB)
  u16* Qp  = (u16*)(ws);                         //  8,388,608 B  [B,H,S,32] bf16
  u16* Kp  = (u16*)(ws + 8388608);               //  8,388,608 B
  u16* Vt  = (u16*)(ws + 16777216);              //  8,388,608 B  [B,H,32,S] bf16
  u16* Z   = (u16*)(ws + 25165824);              //  8,388,608 B  [B*S, 512] bf16
  u16* WT  = (u16*)(ws + 33554432);              //  3,145,728 B  [3][512][1024] bf16
  u16* WoT = (u16*)(ws + 36700160);              //  1,048,576 B  [1024][512] bf16
  unsigned long long* mb = (unsigned long long*)(ws + 37748736);  // 2,097,152 B mask bits
  int* flag = (int*)(ws + 39845888);

  detect_mask_kernel<<<1, 256, 0, stream>>>(mask, flag);
  pack_mask_kernel<<<65536, 256, 0, stream>>>(mask, flag, mb);
  prep_weights_kernel<<<8192, 256, 0, stream>>>(Wq, Wk, Wv, Wo, WT, WoT);
  gemm_proj_kernel<<<dim3(64,4,3), 256, 0, stream>>>(q, k, v, WT, Qp, Kp, Vt);
  attn_kernel<<<dim3(32,64), 256, 0, stream>>>(Qp, Kp, Vt, mb, Z);
  gemm_out_kernel<<<dim3(64,8), 256, 0, stream>>>(Z, WoT, out);
  (void)in_sizes; (void)n_in; (void)out_size; (void)ws_size;
}

// Round 2
// 235.994 us; speedup vs baseline: 1.3697x; 1.3697x over previous
//
#include <hip/hip_runtime.h>
#include <hip/hip_bf16.h>
#include <math.h>

// B=4, S=2048, D_MODEL=1024, H=16, HD=32, SCALE=8.0
typedef unsigned short u16;
typedef unsigned int u32;
typedef __attribute__((ext_vector_type(8))) short s16x8;
typedef __attribute__((ext_vector_type(4))) short s16x4;
typedef __attribute__((ext_vector_type(4))) float f32x4;
typedef __attribute__((ext_vector_type(16))) float f32x16;

#define DEV static __device__ __forceinline__

DEV u16 f2bf(float f){
  __hip_bfloat16 h = __float2bfloat16(f);
  return *reinterpret_cast<u16*>(&h);
}

DEV u32 cvt_pk_bf16(float lo, float hi_){
  u32 r;
  asm("v_cvt_pk_bf16_f32 %0, %1, %2" : "=v"(r) : "v"(lo), "v"(hi_));
  return r;  // low16 = bf16(lo), high16 = bf16(hi_)
}

// ---------------- mask dtype detect ----------------
__global__ void detect_mask_kernel(const unsigned char* __restrict__ m, int* __restrict__ flag){
  __shared__ int cnt;
  if (threadIdx.x==0) cnt=0;
  __syncthreads();
  int nz=0;
  for (int i=threadIdx.x;i<4096;i+=256) nz += (m[(size_t)i*4+1]!=0)?1:0;
  if (nz) atomicAdd(&cnt, nz);
  __syncthreads();
  if (threadIdx.x==0) *flag = (cnt==0)?4:1;   // 4: int32 mask (LSB), 1: bool/uint8
}

// ---------------- mask bit-pack: 16 elements per thread -> u16 word ----------------
__global__ __launch_bounds__(256) void pack_mask_kernel(const unsigned char* __restrict__ m,
    const int* __restrict__ flag, u16* __restrict__ mb16){
  const int stride = *flag;
  const size_t gid = (size_t)blockIdx.x*256u + threadIdx.x;   // 1,048,576 threads
  u32 bits = 0;
  if (stride == 1){
    const uint4 v = *(const uint4*)(m + gid*16);
    bits  =  ((v.x & 0x01010101u) * 0x01020408u) >> 24;
    bits |= (((v.y & 0x01010101u) * 0x01020408u) >> 24) << 4;
    bits |= (((v.z & 0x01010101u) * 0x01020408u) >> 24) << 8;
    bits |= (((v.w & 0x01010101u) * 0x01020408u) >> 24) << 12;
  } else {
    const unsigned char* mm = m + gid*64;
    const uint4 a = *(const uint4*)(mm);
    const uint4 b = *(const uint4*)(mm+16);
    const uint4 c = *(const uint4*)(mm+32);
    const uint4 d = *(const uint4*)(mm+48);
    bits  = (u32)(a.x!=0) | ((u32)(a.y!=0)<<1) | ((u32)(a.z!=0)<<2) | ((u32)(a.w!=0)<<3)
          | ((u32)(b.x!=0)<<4) | ((u32)(b.y!=0)<<5) | ((u32)(b.z!=0)<<6) | ((u32)(b.w!=0)<<7)
          | ((u32)(c.x!=0)<<8) | ((u32)(c.y!=0)<<9) | ((u32)(c.z!=0)<<10)| ((u32)(c.w!=0)<<11)
          | ((u32)(d.x!=0)<<12)| ((u32)(d.y!=0)<<13)| ((u32)(d.z!=0)<<14)| ((u32)(d.w!=0)<<15);
  }
  mb16[gid] = (u16)bits;
}

// ---------------- weight prep: bf16 + [n][k] transpose; Wq pre-scaled by 0.125*log2(e) ----------------
__global__ __launch_bounds__(256) void prep_weights_kernel(
    const float* __restrict__ Wq, const float* __restrict__ Wk, const float* __restrict__ Wv,
    const float* __restrict__ Wo, u16* __restrict__ WT, u16* __restrict__ WoT){
  int gid = blockIdx.x*256 + threadIdx.x;
  if (gid < 3*512*1024){
    int z = gid >> 19;
    int r = gid & ((1<<19)-1);
    int n = r >> 10, d = r & 1023;
    const float* W = (z==0)?Wq:((z==1)?Wk:Wv);
    int h = n>>5, e = n&31;
    float wv = W[((size_t)h*1024 + (size_t)d)*32 + e];
    if (z==0) wv *= 0.18033688011112042f;   // (1/sqrt(64)) * log2(e)
    WT[gid] = f2bf(wv);
  } else {
    int r = gid - 3*512*1024;
    int n = r >> 9, cc = r & 511;
    WoT[r] = f2bf(Wo[(size_t)cc*1024 + n]);
  }
}

// ---------------- projection GEMM: [8192x1024]f32 x WT[n][k] -> Q/K (bf16 [B,H,S,32]) or V^T (bf16 [B,H,32,S])
__global__ __launch_bounds__(256) void gemm_proj_kernel(
    const float* __restrict__ Aq, const float* __restrict__ Ak, const float* __restrict__ Av,
    const u16* __restrict__ WT, u16* __restrict__ Qp, u16* __restrict__ Kp, u16* __restrict__ Vt)
{
  __shared__ u16 As[128*64];
  __shared__ u16 Bs[128*64];
  const int z = blockIdx.z;
  const float* __restrict__ A = (z==0)?Aq:((z==1)?Ak:Av);
  const u16* __restrict__ W = WT + (size_t)z*(512*1024);
  const int m0 = blockIdx.x*128, n0 = blockIdx.y*128;
  const int t = threadIdx.x, lane = t&63, wv = t>>6;
  const int wr = wv>>1, wc = wv&1;
  const int c = lane&15, g = lane>>4;
  f32x4 acc[4][4] = {};
  for (int kk=0; kk<1024; kk+=64){
    #pragma unroll
    for (int j=0;j<8;j++){                       // A: 128x64 f32 -> bf16 LDS (swizzled)
      int idx = t + j*256;
      int row = idx>>4, kq=(idx&15)<<2;
      f32x4 a4 = *(const f32x4*)(A + (size_t)(m0+row)*1024 + kk + kq);
      s16x4 b4;
      b4[0]=(short)f2bf(a4[0]); b4[1]=(short)f2bf(a4[1]);
      b4[2]=(short)f2bf(a4[2]); b4[3]=(short)f2bf(a4[3]);
      int co = (kq<<1) ^ ((row&7)<<4);
      *(s16x4*)((char*)As + row*128 + co) = b4;
    }
    #pragma unroll
    for (int j=0;j<4;j++){                       // B: 128x64 bf16
      int idx = t + j*256;
      int n = idx>>3, k8=(idx&7)<<3;
      s16x8 bv = *(const s16x8*)(W + (size_t)(n0+n)*1024 + kk + k8);
      int co = (k8<<1) ^ ((n&7)<<4);
      *(s16x8*)((char*)Bs + n*128 + co) = bv;
    }
    __syncthreads();
    #pragma unroll
    for (int ks=0;ks<2;ks++){
      s16x8 af[4], bf[4];
      #pragma unroll
      for (int i=0;i<4;i++){
        int ra = wr*64 + i*16 + c;
        af[i] = *(const s16x8*)((const char*)As + ra*128 + ((ks*64 + g*16) ^ ((ra&7)<<4)));
        int rb = wc*64 + i*16 + c;
        bf[i] = *(const s16x8*)((const char*)Bs + rb*128 + ((ks*64 + g*16) ^ ((rb&7)<<4)));
      }
      #pragma unroll
      for (int mi=0;mi<4;mi++)
        #pragma unroll
        for (int nj=0;nj<4;nj++)
          acc[mi][nj] = __builtin_amdgcn_mfma_f32_16x16x32_bf16(af[mi], bf[nj], acc[mi][nj], 0, 0, 0);
    }
    __syncthreads();
  }
  #pragma unroll
  for (int mi=0;mi<4;mi++){
    #pragma unroll
    for (int nj=0;nj<4;nj++){
      #pragma unroll
      for (int r=0;r<4;r++){
        int gm = m0 + wr*64 + mi*16 + g*4 + r;
        int gn = n0 + wc*64 + nj*16 + c;
        u16 val = f2bf(acc[mi][nj][r]);
        int b = gm>>11, s = gm&2047, hh = gn>>5, e = gn&31;
        if (z==0)      Qp[((size_t)(b*16+hh)*2048 + s)*32 + e] = val;
        else if (z==1) Kp[((size_t)(b*16+hh)*2048 + s)*32 + e] = val;
        else           Vt[((size_t)(b*16+hh)*32 + e)*2048 + s] = val;
      }
    }
  }
}

// ---------------- flash attention: swapped-operand 32x32, in-register softmax ----------------
// Each wave: 32 q-rows, full K sweep in KVBLK=32 tiles. q = lane&31 everywhere.
__global__ __launch_bounds__(256, 4) void attn_kernel(
    const u16* __restrict__ Qp, const u16* __restrict__ Kp, const u16* __restrict__ Vt,
    const u32* __restrict__ mb32, u16* __restrict__ Z)
{
  __shared__ float Osh[4][32][36];
  const int t = threadIdx.x, lane = t&63, wid = t>>6;
  const int c = lane&31, hi = lane>>5;
  const int hi8 = hi*8;
  // XCD-aware swizzle: all 16 q-tiles of one bh land on one XCD
  const int wg = blockIdx.x;            // 0..1023
  const int xcd = wg & 7, loc = wg >> 3;
  const int bh = xcd*8 + (loc>>4);
  const int qb = loc & 15;
  const int b = bh>>4, h = bh&15;
  const int q0 = qb*128 + wid*32;
  const u16* Qh = Qp + (size_t)bh*2048*32;
  const u16* Kh = Kp + (size_t)bh*2048*32;
  const u16* Vh = Vt + (size_t)bh*32*2048;

  // Q B-frag: col=q=c, k-dim = hd = hs*16 + hi*8 + i   (Q pre-scaled by 0.125*log2e)
  const s16x8 qf0 = *(const s16x8*)(Qh + (size_t)(q0 + c)*32 + hi8);
  const s16x8 qf1 = *(const s16x8*)(Qh + (size_t)(q0 + c)*32 + 16 + hi8);

  const f32x16 z16 = {0,0,0,0,0,0,0,0,0,0,0,0,0,0,0,0};
  f32x16 O = z16;
  float mrun = -INFINITY, lrun = 0.f;
  const u32* mrowp = mb32 + ((size_t)b*2048 + (size_t)(q0 + c))*64;  // 64 u32 words per q-row

  for (int kb=0; kb<2048; kb+=32){
    // K A-frag: row = k-local = c, k-dim = hd
    const s16x8 kf0 = *(const s16x8*)(Kh + (size_t)(kb + c)*32 + hi8);
    const s16x8 kf1 = *(const s16x8*)(Kh + (size_t)(kb + c)*32 + 16 + hi8);
    // V^T A-frag: row = hd = c, k-dim = k-local = 16s + hi*8 + i
    const s16x8 vf0 = *(const s16x8*)(Vh + (size_t)c*2048 + kb + hi8);
    const s16x8 vf1 = *(const s16x8*)(Vh + (size_t)c*2048 + kb + 16 + hi8);
    const u32 mw = mrowp[kb>>5];

    // S^T[k][q]: lane holds k = (r&3)+8*(r>>2)+4*hi for its q=c (log2-scaled scores)
    f32x16 p = __builtin_amdgcn_mfma_f32_32x32x16_bf16(kf0, qf0, z16, 0, 0, 0);
    p = __builtin_amdgcn_mfma_f32_32x32x16_bf16(kf1, qf1, p, 0, 0, 0);

    // mask (True = masked -> -1e10)
    const u32 ms = mw >> (4*hi);
    #pragma unroll
    for (int r=0;r<16;r++){
      const int cpos = (r&3) + 8*(r>>2);
      if ((ms >> cpos) & 1u) p[r] = -1e10f;
    }
    // row max: in-register tree + one cross-half shuffle
    float mx8[8];
    #pragma unroll
    for (int i=0;i<8;i++) mx8[i] = fmaxf(p[i], p[i+8]);
    #pragma unroll
    for (int i=0;i<4;i++) mx8[i] = fmaxf(mx8[i], mx8[i+4]);
    float mx = fmaxf(fmaxf(mx8[0],mx8[1]), fmaxf(mx8[2],mx8[3]));
    mx = fmaxf(mx, __shfl_xor(mx, 32));
    const float nm = fmaxf(mrun, mx);
    const float fr = exp2f(mrun - nm);
    mrun = nm;
    // exp2
    #pragma unroll
    for (int r=0;r<16;r++) p[r] = exp2f(p[r] - nm);
    // row sum
    float s8[8];
    #pragma unroll
    for (int i=0;i<8;i++) s8[i] = p[i] + p[i+8];
    #pragma unroll
    for (int i=0;i<4;i++) s8[i] += s8[i+4];
    float own = (s8[0]+s8[1]) + (s8[2]+s8[3]);
    const float rs = own + __shfl_xor(own, 32);
    lrun = lrun*fr + rs;
    #pragma unroll
    for (int r=0;r<16;r++) O[r] *= fr;

    // P^T B-frag build: pack pairs to bf16 words, swap halves across lane^32, select
    u32 pw[8], sw[8];
    #pragma unroll
    for (int u=0;u<8;u++) pw[u] = cvt_pk_bf16(p[2*u], p[2*u+1]);
    #pragma unroll
    for (int u=0;u<8;u++) sw[u] = __shfl_xor(pw[u], 32);
    const bool hb = (hi != 0);
    union { u32 u[4]; s16x8 v; } bf0, bf1;
    bf0.u[0] = hb ? sw[2] : pw[0];
    bf0.u[1] = hb ? sw[3] : pw[1];
    bf0.u[2] = hb ? pw[2] : sw[0];
    bf0.u[3] = hb ? pw[3] : sw[1];
    bf1.u[0] = hb ? sw[6] : pw[4];
    bf1.u[1] = hb ? sw[7] : pw[5];
    bf1.u[2] = hb ? pw[6] : sw[4];
    bf1.u[3] = hb ? pw[7] : sw[5];

    // O^T += V^T * P^T : col = q = c, rows = hd pattern
    O = __builtin_amdgcn_mfma_f32_32x32x16_bf16(vf0, bf0.v, O, 0, 0, 0);
    O = __builtin_amdgcn_mfma_f32_32x32x16_bf16(vf1, bf1.v, O, 0, 0, 0);
  }

  // epilogue: normalize (per-lane scalar!) and transpose via LDS for coalesced Z stores
  const float linv = 1.0f / lrun;
  #pragma unroll
  for (int r=0;r<16;r++){
    const int hd = (r&3) + 8*(r>>2) + 4*hi;
    Osh[wid][c][hd] = O[r] * linv;
  }
  __syncthreads();
  const int rq = lane >> 1, rc0 = (lane & 1)*16;
  const float* orow = &Osh[wid][rq][0];
  union { u16 q[8]; s16x8 v; } o0, o1;
  #pragma unroll
  for (int j=0;j<8;j++){ o0.q[j] = f2bf(orow[rc0+j]); o1.q[j] = f2bf(orow[rc0+8+j]); }
  u16* zp = Z + ((size_t)b*2048 + (size_t)(q0 + rq))*512 + h*32 + rc0;
  *(s16x8*)(zp)   = o0.v;
  *(s16x8*)(zp+8) = o1.v;
}

// ---------------- output GEMM: Z[8192x512]bf16 x WoT[1024][512] -> out f32 ----------------
__global__ __launch_bounds__(256) void gemm_out_kernel(
    const u16* __restrict__ Zb, const u16* __restrict__ WoT, float* __restrict__ out)
{
  __shared__ u16 As[128*64];
  __shared__ u16 Bs[128*64];
  const int m0 = blockIdx.x*128, n0 = blockIdx.y*128;
  const int t = threadIdx.x, lane=t&63, wv=t>>6;
  const int wr=wv>>1, wc=wv&1, c=lane&15, g=lane>>4;
  f32x4 acc[4][4] = {};
  for (int kk=0; kk<512; kk+=64){
    #pragma unroll
    for (int j=0;j<4;j++){
      int idx = t + j*256;
      int row = idx>>3, k8=(idx&7)<<3;
      int co = (k8<<1) ^ ((row&7)<<4);
      s16x8 av = *(const s16x8*)(Zb + (size_t)(m0+row)*512 + kk + k8);
      *(s16x8*)((char*)As + row*128 + co) = av;
      s16x8 bv = *(const s16x8*)(WoT + (size_t)(n0+row)*512 + kk + k8);
      *(s16x8*)((char*)Bs + row*128 + co) = bv;
    }
    __syncthreads();
    #pragma unroll
    for (int ks=0;ks<2;ks++){
      s16x8 af[4], bf[4];
      #pragma unroll
      for (int i=0;i<4;i++){
        int ra = wr*64 + i*16 + c;
        af[i] = *(const s16x8*)((const char*)As + ra*128 + ((ks*64 + g*16) ^ ((ra&7)<<4)));
        int rb = wc*64 + i*16 + c;
        bf[i] = *(const s16x8*)((const char*)Bs + rb*128 + ((ks*64 + g*16) ^ ((rb&7)<<4)));
      }
      #pragma unroll
      for (int mi=0;mi<4;mi++)
        #pragma unroll
        for (int nj=0;nj<4;nj++)
          acc[mi][nj] = __builtin_amdgcn_mfma_f32_16x16x32_bf16(af[mi], bf[nj], acc[mi][nj], 0, 0, 0);
    }
    __syncthreads();
  }
  #pragma unroll
  for (int mi=0;mi<4;mi++)
    #pragma unroll
    for (int nj=0;nj<4;nj++)
      #pragma unroll
      for (int r=0;r<4;r++){
        int gm = m0 + wr*64 + mi*16 + g*4 + r;
        int gn = n0 + wc*64 + nj*16 + c;
        out[(size_t)gm*1024 + gn] = acc[mi][nj][r];
      }
}

// ---------------- launcher ----------------
extern "C" void kernel_launch(void* const* d_in, const int* in_sizes, int n_in,
                              void* d_out, int out_size, void* d_ws, size_t ws_size,
                              hipStream_t stream)
{
  const float* q  = (const float*)d_in[0];
  const float* k  = (const float*)d_in[1];
  const float* v  = (const float*)d_in[2];
  const unsigned char* mask = (const unsigned char*)d_in[3];
  const float* Wq = (const float*)d_in[4];
  const float* Wk = (const float*)d_in[5];
  const float* Wv = (const float*)d_in[6];
  const float* Wo = (const float*)d_in[7];
  float* out = (float*)d_out;

  char* ws = (char*)d_ws;
  u16* Qp  = (u16*)(ws);                         //  8,388,608 B  [B,H,S,32] bf16
  u16* Kp  = (u16*)(ws + 8388608);               //  8,388,608 B
  u16* Vt  = (u16*)(ws + 16777216);              //  8,388,608 B  [B,H,32,S] bf16
  u16* Z   = (u16*)(ws + 25165824);              //  8,388,608 B  [B*S, 512] bf16
  u16* WT  = (u16*)(ws + 33554432);              //  3,145,728 B  [3][512][1024] bf16
  u16* WoT = (u16*)(ws + 36700160);              //  1,048,576 B  [1024][512] bf16
  u16* mb16 = (u16*)(ws + 37748736);             //  2,097,152 B  mask bits
  int* flag = (int*)(ws + 39845888);

  detect_mask_kernel<<<1, 256, 0, stream>>>(mask, flag);
  pack_mask_kernel<<<4096, 256, 0, stream>>>(mask, flag, mb16);
  prep_weights_kernel<<<8192, 256, 0, stream>>>(Wq, Wk, Wv, Wo, WT, WoT);
  gemm_proj_kernel<<<dim3(64,4,3), 256, 0, stream>>>(q, k, v, WT, Qp, Kp, Vt);
  attn_kernel<<<1024, 256, 0, stream>>>(Qp, Kp, Vt, (const u32*)mb16, Z);
  gemm_out_kernel<<<dim3(64,8), 256, 0, stream>>>(Z, WoT, out);
  (void)in_sizes; (void)n_in; (void)out_size; (void)ws_size;
}

// Round 4
// 208.894 us; speedup vs baseline: 1.5474x; 1.1297x over previous
//
#include <hip/hip_runtime.h>
#include <hip/hip_bf16.h>
#include <math.h>

// B=4, S=2048, D_MODEL=1024, H=16, HD=32, SCALE=8.0
typedef unsigned short u16;
typedef unsigned int u32;
typedef unsigned long long u64;
typedef __attribute__((ext_vector_type(8))) short s16x8;
typedef __attribute__((ext_vector_type(4))) short s16x4;
typedef __attribute__((ext_vector_type(4))) float f32x4;
typedef __attribute__((ext_vector_type(16))) float f32x16;
typedef __attribute__((ext_vector_type(2))) unsigned int u32x2;

#define DEV static __device__ __forceinline__

DEV u16 f2bf(float f){
  __hip_bfloat16 h = __float2bfloat16(f);
  return *reinterpret_cast<u16*>(&h);
}

DEV u32 cvt_pk_bf16(float lo, float hi_){
  u32 r;
  asm("v_cvt_pk_bf16_f32 %0, %1, %2" : "=v"(r) : "v"(lo), "v"(hi_));
  return r;  // low16 = bf16(lo), high16 = bf16(hi_)
}

// SSA-clean permlane32 swap: returns {a.lo||b.lo, a.hi||b.hi}
DEV u32x2 pl32swap(u32 a, u32 b){
  return __builtin_amdgcn_permlane32_swap(a, b, false, false);
}
DEV float xhalf_max(float x){
  u32x2 r = pl32swap(__float_as_uint(x), __float_as_uint(x));
  return fmaxf(__uint_as_float(r[0]), __uint_as_float(r[1]));
}
DEV float xhalf_sum(float x){
  u32x2 r = pl32swap(__float_as_uint(x), __float_as_uint(x));
  return __uint_as_float(r[0]) + __uint_as_float(r[1]);
}

// ---------------- mask dtype detect ----------------
__global__ void detect_mask_kernel(const unsigned char* __restrict__ m, int* __restrict__ flag){
  __shared__ int cnt;
  if (threadIdx.x==0) cnt=0;
  __syncthreads();
  int nz=0;
  for (int i=threadIdx.x;i<4096;i+=256) nz += (m[(size_t)i*4+1]!=0)?1:0;
  if (nz) atomicAdd(&cnt, nz);
  __syncthreads();
  if (threadIdx.x==0) *flag = (cnt==0)?4:1;   // 4: int32 mask (LSB), 1: bool/uint8
}

// ---------------- mask bit-pack: 16 elements per thread -> u16 word ----------------
__global__ __launch_bounds__(256) void pack_mask_kernel(const unsigned char* __restrict__ m,
    const int* __restrict__ flag, u16* __restrict__ mb16){
  const int stride = *flag;
  const size_t gid = (size_t)blockIdx.x*256u + threadIdx.x;   // 1,048,576 threads
  u32 bits = 0;
  if (stride == 1){
    const uint4 v = *(const uint4*)(m + gid*16);
    bits  =  ((v.x & 0x01010101u) * 0x01020408u) >> 24;
    bits |= (((v.y & 0x01010101u) * 0x01020408u) >> 24) << 4;
    bits |= (((v.z & 0x01010101u) * 0x01020408u) >> 24) << 8;
    bits |= (((v.w & 0x01010101u) * 0x01020408u) >> 24) << 12;
  } else {
    const unsigned char* mm = m + gid*64;
    const uint4 a = *(const uint4*)(mm);
    const uint4 b = *(const uint4*)(mm+16);
    const uint4 c = *(const uint4*)(mm+32);
    const uint4 d = *(const uint4*)(mm+48);
    bits  = (u32)(a.x!=0) | ((u32)(a.y!=0)<<1) | ((u32)(a.z!=0)<<2) | ((u32)(a.w!=0)<<3)
          | ((u32)(b.x!=0)<<4) | ((u32)(b.y!=0)<<5) | ((u32)(b.z!=0)<<6) | ((u32)(b.w!=0)<<7)
          | ((u32)(c.x!=0)<<8) | ((u32)(c.y!=0)<<9) | ((u32)(c.z!=0)<<10)| ((u32)(c.w!=0)<<11)
          | ((u32)(d.x!=0)<<12)| ((u32)(d.y!=0)<<13)| ((u32)(d.z!=0)<<14)| ((u32)(d.w!=0)<<15);
  }
  mb16[gid] = (u16)bits;
}

// ---------------- weight prep: bf16 + [n][k] transpose; Wq pre-scaled by 0.125*log2(e) ----------------
__global__ __launch_bounds__(256) void prep_weights_kernel(
    const float* __restrict__ Wq, const float* __restrict__ Wk, const float* __restrict__ Wv,
    const float* __restrict__ Wo, u16* __restrict__ WT, u16* __restrict__ WoT){
  int gid = blockIdx.x*256 + threadIdx.x;
  if (gid < 3*512*1024){
    int z = gid >> 19;
    int r = gid & ((1<<19)-1);
    int n = r >> 10, d = r & 1023;
    const float* W = (z==0)?Wq:((z==1)?Wk:Wv);
    int h = n>>5, e = n&31;
    float wv = W[((size_t)h*1024 + (size_t)d)*32 + e];
    if (z==0) wv *= 0.18033688011112042f;   // (1/sqrt(64)) * log2(e)
    WT[gid] = f2bf(wv);
  } else {
    int r = gid - 3*512*1024;
    int n = r >> 9, cc = r & 511;
    WoT[r] = f2bf(Wo[(size_t)cc*1024 + n]);
  }
}

// ---------------- projection GEMM: [8192x1024]f32 x WT[n][k] -> Q/K (bf16 [B,H,S,32]) or V^T (bf16 [B,H,32,S])
__global__ __launch_bounds__(256) void gemm_proj_kernel(
    const float* __restrict__ Aq, const float* __restrict__ Ak, const float* __restrict__ Av,
    const u16* __restrict__ WT, u16* __restrict__ Qp, u16* __restrict__ Kp, u16* __restrict__ Vt)
{
  __shared__ u16 As[128*64];
  __shared__ u16 Bs[128*64];
  const int z = blockIdx.z;
  const float* __restrict__ A = (z==0)?Aq:((z==1)?Ak:Av);
  const u16* __restrict__ W = WT + (size_t)z*(512*1024);
  const int m0 = blockIdx.x*128, n0 = blockIdx.y*128;
  const int t = threadIdx.x, lane = t&63, wv = t>>6;
  const int wr = wv>>1, wc = wv&1;
  const int c = lane&15, g = lane>>4;
  f32x4 acc[4][4] = {};
  for (int kk=0; kk<1024; kk+=64){
    #pragma unroll
    for (int j=0;j<8;j++){                       // A: 128x64 f32 -> bf16 LDS (swizzled)
      int idx = t + j*256;
      int row = idx>>4, kq=(idx&15)<<2;
      f32x4 a4 = *(const f32x4*)(A + (size_t)(m0+row)*1024 + kk + kq);
      s16x4 b4;
      b4[0]=(short)f2bf(a4[0]); b4[1]=(short)f2bf(a4[1]);
      b4[2]=(short)f2bf(a4[2]); b4[3]=(short)f2bf(a4[3]);
      int co = (kq<<1) ^ ((row&7)<<4);
      *(s16x4*)((char*)As + row*128 + co) = b4;
    }
    #pragma unroll
    for (int j=0;j<4;j++){                       // B: 128x64 bf16
      int idx = t + j*256;
      int n = idx>>3, k8=(idx&7)<<3;
      s16x8 bv = *(const s16x8*)(W + (size_t)(n0+n)*1024 + kk + k8);
      int co = (k8<<1) ^ ((n&7)<<4);
      *(s16x8*)((char*)Bs + n*128 + co) = bv;
    }
    __syncthreads();
    #pragma unroll
    for (int ks=0;ks<2;ks++){
      s16x8 af[4], bf[4];
      #pragma unroll
      for (int i=0;i<4;i++){
        int ra = wr*64 + i*16 + c;
        af[i] = *(const s16x8*)((const char*)As + ra*128 + ((ks*64 + g*16) ^ ((ra&7)<<4)));
        int rb = wc*64 + i*16 + c;
        bf[i] = *(const s16x8*)((const char*)Bs + rb*128 + ((ks*64 + g*16) ^ ((rb&7)<<4)));
      }
      #pragma unroll
      for (int mi=0;mi<4;mi++)
        #pragma unroll
        for (int nj=0;nj<4;nj++)
          acc[mi][nj] = __builtin_amdgcn_mfma_f32_16x16x32_bf16(af[mi], bf[nj], acc[mi][nj], 0, 0, 0);
    }
    __syncthreads();
  }
  #pragma unroll
  for (int mi=0;mi<4;mi++){
    #pragma unroll
    for (int nj=0;nj<4;nj++){
      #pragma unroll
      for (int r=0;r<4;r++){
        int gm = m0 + wr*64 + mi*16 + g*4 + r;
        int gn = n0 + wc*64 + nj*16 + c;
        u16 val = f2bf(acc[mi][nj][r]);
        int b = gm>>11, s = gm&2047, hh = gn>>5, e = gn&31;
        if (z==0)      Qp[((size_t)(b*16+hh)*2048 + s)*32 + e] = val;
        else if (z==1) Kp[((size_t)(b*16+hh)*2048 + s)*32 + e] = val;
        else           Vt[((size_t)(b*16+hh)*32 + e)*2048 + s] = val;
      }
    }
  }
}

// ---------------- flash attention: swapped 32x32, KVBLK=64, prefetch, defer-max, permlane builtin ----------------
__global__ __launch_bounds__(256, 4) void attn_kernel(
    const u16* __restrict__ Qp, const u16* __restrict__ Kp, const u16* __restrict__ Vt,
    const u32* __restrict__ mb32, u16* __restrict__ Z)
{
  __shared__ float Osh[4][32][36];
  const int t = threadIdx.x, lane = t&63, wid = t>>6;
  const int c = lane&31, hi = lane>>5;
  const int hi8 = hi*8;
  // XCD-aware swizzle: all 16 q-tiles of one bh land on one XCD
  const int wg = blockIdx.x;            // 0..1023
  const int xcd = wg & 7, loc = wg >> 3;
  const int bh = xcd*8 + (loc>>4);
  const int qb = loc & 15;
  const int b = bh>>4, h = bh&15;
  const int q0 = qb*128 + wid*32;
  const u16* Qh = Qp + (size_t)bh*2048*32;
  const u16* Kh = Kp + (size_t)bh*2048*32;
  const u16* Vh = Vt + (size_t)bh*32*2048;

  // Q B-frag: col=q=c, k-dim = hd  (Q pre-scaled by 0.125*log2e)
  const s16x8 qf0 = *(const s16x8*)(Qh + (size_t)(q0 + c)*32 + hi8);
  const s16x8 qf1 = *(const s16x8*)(Qh + (size_t)(q0 + c)*32 + 16 + hi8);

  const f32x16 z16 = {0,0,0,0,0,0,0,0,0,0,0,0,0,0,0,0};
  f32x16 O = z16;
  float mrun = -INFINITY, lrun = 0.f;
  const u32* mrowp = mb32 + ((size_t)b*2048 + (size_t)(q0 + c))*64;  // 64 u32 words per q-row

  auto loadK4 = [&](int kb, s16x8 &f0, s16x8 &f1, s16x8 &f2, s16x8 &f3){
    const u16* kbase = Kh + (size_t)(kb + c)*32 + hi8;
    f0 = *(const s16x8*)(kbase);            // k-rows kb+c,   hd 0..15 slice
    f1 = *(const s16x8*)(kbase + 16);       //                hd 16..31 slice
    f2 = *(const s16x8*)(kbase + 1024);     // k-rows kb+32+c
    f3 = *(const s16x8*)(kbase + 1040);
  };

  // one 64-column tile: QK^T (swapped), mask, online softmax, P^T build, PV (swapped)
  auto tile = [&](const s16x8 &kf0, const s16x8 &kf1, const s16x8 &kf2, const s16x8 &kf3,
                  int kb, u32 mA, u32 mB){
    const u16* vbase = Vh + (size_t)c*2048 + kb + hi8;
    const s16x8 vf0 = *(const s16x8*)(vbase);
    const s16x8 vf1 = *(const s16x8*)(vbase + 16);
    const s16x8 vf2 = *(const s16x8*)(vbase + 32);
    const s16x8 vf3 = *(const s16x8*)(vbase + 48);

    f32x16 p0 = __builtin_amdgcn_mfma_f32_32x32x16_bf16(kf0, qf0, z16, 0, 0, 0);
    p0 = __builtin_amdgcn_mfma_f32_32x32x16_bf16(kf1, qf1, p0, 0, 0, 0);
    f32x16 p1 = __builtin_amdgcn_mfma_f32_32x32x16_bf16(kf2, qf0, z16, 0, 0, 0);
    p1 = __builtin_amdgcn_mfma_f32_32x32x16_bf16(kf3, qf1, p1, 0, 0, 0);

    const u32 msA = mA >> (4*hi), msB = mB >> (4*hi);
    #pragma unroll
    for (int r=0;r<16;r++){
      const int cpos = (r&3) + 8*(r>>2);
      if ((msA >> cpos) & 1u) p0[r] = -1e10f;
      if ((msB >> cpos) & 1u) p1[r] = -1e10f;
    }
    // tile max over 64 cols (in-register tree + one cross-half permlane reduce)
    float m8[8];
    #pragma unroll
    for (int i=0;i<8;i++) m8[i] = fmaxf(fmaxf(p0[i], p0[i+8]), fmaxf(p1[i], p1[i+8]));
    #pragma unroll
    for (int i=0;i<4;i++) m8[i] = fmaxf(m8[i], m8[i+4]);
    float mx = fmaxf(fmaxf(m8[0],m8[1]), fmaxf(m8[2],m8[3]));
    mx = xhalf_max(mx);

    // defer-max: only rescale when the running max actually grows past THR=8 (log2 units)
    if (__any(mx > mrun + 8.f)){
      const float nm = fmaxf(mrun, mx);
      const float fr = __builtin_amdgcn_exp2f(mrun - nm);
      mrun = nm;
      lrun *= fr;
      #pragma unroll
      for (int r=0;r<16;r++) O[r] *= fr;
    }
    #pragma unroll
    for (int r=0;r<16;r++){
      p0[r] = __builtin_amdgcn_exp2f(p0[r] - mrun);
      p1[r] = __builtin_amdgcn_exp2f(p1[r] - mrun);
    }
    float s8[8];
    #pragma unroll
    for (int i=0;i<8;i++) s8[i] = (p0[i] + p0[i+8]) + (p1[i] + p1[i+8]);
    #pragma unroll
    for (int i=0;i<4;i++) s8[i] += s8[i+4];
    float own = (s8[0]+s8[1]) + (s8[2]+s8[3]);
    lrun += xhalf_sum(own);

    // P^T B-frags fully in-register: cvt_pk pairs + permlane swaps (SSA builtin)
    u32 pwA[8], pwB[8];
    #pragma unroll
    for (int u=0;u<8;u++){ pwA[u] = cvt_pk_bf16(p0[2*u], p0[2*u+1]); pwB[u] = cvt_pk_bf16(p1[2*u], p1[2*u+1]); }
    u32x2 a02 = pl32swap(pwA[0], pwA[2]);
    u32x2 a13 = pl32swap(pwA[1], pwA[3]);
    u32x2 a46 = pl32swap(pwA[4], pwA[6]);
    u32x2 a57 = pl32swap(pwA[5], pwA[7]);
    u32x2 b02 = pl32swap(pwB[0], pwB[2]);
    u32x2 b13 = pl32swap(pwB[1], pwB[3]);
    u32x2 b46 = pl32swap(pwB[4], pwB[6]);
    u32x2 b57 = pl32swap(pwB[5], pwB[7]);
    union { u32 u[4]; s16x8 v; } fA0 = {{a02[0], a13[0], a02[1], a13[1]}};
    union { u32 u[4]; s16x8 v; } fA1 = {{a46[0], a57[0], a46[1], a57[1]}};
    union { u32 u[4]; s16x8 v; } fB0 = {{b02[0], b13[0], b02[1], b13[1]}};
    union { u32 u[4]; s16x8 v; } fB1 = {{b46[0], b57[0], b46[1], b57[1]}};

    O = __builtin_amdgcn_mfma_f32_32x32x16_bf16(vf0, fA0.v, O, 0, 0, 0);
    O = __builtin_amdgcn_mfma_f32_32x32x16_bf16(vf1, fA1.v, O, 0, 0, 0);
    O = __builtin_amdgcn_mfma_f32_32x32x16_bf16(vf2, fB0.v, O, 0, 0, 0);
    O = __builtin_amdgcn_mfma_f32_32x32x16_bf16(vf3, fB1.v, O, 0, 0, 0);
  };

  // 2-stage software pipeline over 64-col tiles (manual unroll-2, named buffers)
  s16x8 ka0, ka1, ka2, ka3;
  loadK4(0, ka0, ka1, ka2, ka3);
  u64 mwa = *(const u64*)(mrowp);
  for (int kb = 0; kb < 2048; kb += 128){
    s16x8 kb0, kb1, kb2, kb3;
    loadK4(kb + 64, kb0, kb1, kb2, kb3);
    u64 mwb = *(const u64*)(mrowp + ((kb + 64) >> 5));
    tile(ka0, ka1, ka2, ka3, kb, (u32)mwa, (u32)(mwa >> 32));
    const int nxt = (kb + 128) & 2047;     // last prefetch wraps (unused), stays in-bounds
    loadK4(nxt, ka0, ka1, ka2, ka3);
    mwa = *(const u64*)(mrowp + (nxt >> 5));
    tile(kb0, kb1, kb2, kb3, kb + 64, (u32)mwb, (u32)(mwb >> 32));
  }

  // epilogue: normalize (per-lane scalar) and transpose via LDS for coalesced Z stores
  const float linv = 1.0f / lrun;
  #pragma unroll
  for (int r=0;r<16;r++){
    const int hd = (r&3) + 8*(r>>2) + 4*hi;
    Osh[wid][c][hd] = O[r] * linv;
  }
  __syncthreads();
  const int rq = lane >> 1, rc0 = (lane & 1)*16;
  const float* orow = &Osh[wid][rq][0];
  union { u16 q[8]; s16x8 v; } o0, o1;
  #pragma unroll
  for (int j=0;j<8;j++){ o0.q[j] = f2bf(orow[rc0+j]); o1.q[j] = f2bf(orow[rc0+8+j]); }
  u16* zp = Z + ((size_t)b*2048 + (size_t)(q0 + rq))*512 + h*32 + rc0;
  *(s16x8*)(zp)   = o0.v;
  *(s16x8*)(zp+8) = o1.v;
}

// ---------------- output GEMM: Z[8192x512]bf16 x WoT[1024][512] -> out f32 ----------------
__global__ __launch_bounds__(256) void gemm_out_kernel(
    const u16* __restrict__ Zb, const u16* __restrict__ WoT, float* __restrict__ out)
{
  __shared__ u16 As[128*64];
  __shared__ u16 Bs[128*64];
  const int m0 = blockIdx.x*128, n0 = blockIdx.y*128;
  const int t = threadIdx.x, lane=t&63, wv=t>>6;
  const int wr=wv>>1, wc=wv&1, c=lane&15, g=lane>>4;
  f32x4 acc[4][4] = {};
  for (int kk=0; kk<512; kk+=64){
    #pragma unroll
    for (int j=0;j<4;j++){
      int idx = t + j*256;
      int row = idx>>3, k8=(idx&7)<<3;
      int co = (k8<<1) ^ ((row&7)<<4);
      s16x8 av = *(const s16x8*)(Zb + (size_t)(m0+row)*512 + kk + k8);
      *(s16x8*)((char*)As + row*128 + co) = av;
      s16x8 bv = *(const s16x8*)(WoT + (size_t)(n0+row)*512 + kk + k8);
      *(s16x8*)((char*)Bs + row*128 + co) = bv;
    }
    __syncthreads();
    #pragma unroll
    for (int ks=0;ks<2;ks++){
      s16x8 af[4], bf[4];
      #pragma unroll
      for (int i=0;i<4;i++){
        int ra = wr*64 + i*16 + c;
        af[i] = *(const s16x8*)((const char*)As + ra*128 + ((ks*64 + g*16) ^ ((ra&7)<<4)));
        int rb = wc*64 + i*16 + c;
        bf[i] = *(const s16x8*)((const char*)Bs + rb*128 + ((ks*64 + g*16) ^ ((rb&7)<<4)));
      }
      #pragma unroll
      for (int mi=0;mi<4;mi++)
        #pragma unroll
        for (int nj=0;nj<4;nj++)
          acc[mi][nj] = __builtin_amdgcn_mfma_f32_16x16x32_bf16(af[mi], bf[nj], acc[mi][nj], 0, 0, 0);
    }
    __syncthreads();
  }
  #pragma unroll
  for (int mi=0;mi<4;mi++)
    #pragma unroll
    for (int nj=0;nj<4;nj++)
      #pragma unroll
      for (int r=0;r<4;r++){
        int gm = m0 + wr*64 + mi*16 + g*4 + r;
        int gn = n0 + wc*64 + nj*16 + c;
        out[(size_t)gm*1024 + gn] = acc[mi][nj][r];
      }
}

// ---------------- launcher ----------------
extern "C" void kernel_launch(void* const* d_in, const int* in_sizes, int n_in,
                              void* d_out, int out_size, void* d_ws, size_t ws_size,
                              hipStream_t stream)
{
  const float* q  = (const float*)d_in[0];
  const float* k  = (const float*)d_in[1];
  const float* v  = (const float*)d_in[2];
  const unsigned char* mask = (const unsigned char*)d_in[3];
  const float* Wq = (const float*)d_in[4];
  const float* Wk = (const float*)d_in[5];
  const float* Wv = (const float*)d_in[6];
  const float* Wo = (const float*)d_in[7];
  float* out = (float*)d_out;

  char* ws = (char*)d_ws;
  u16* Qp  = (u16*)(ws);                         //  8,388,608 B  [B,H,S,32] bf16
  u16* Kp  = (u16*)(ws + 8388608);               //  8,388,608 B
  u16* Vt  = (u16*)(ws + 16777216);              //  8,388,608 B  [B,H,32,S] bf16
  u16* Z   = (u16*)(ws + 25165824);              //  8,388,608 B  [B*S, 512] bf16
  u16* WT  = (u16*)(ws + 33554432);              //  3,145,728 B  [3][512][1024] bf16
  u16* WoT = (u16*)(ws + 36700160);              //  1,048,576 B  [1024][512] bf16
  u16* mb16 = (u16*)(ws + 37748736);             //  2,097,152 B  mask bits
  int* flag = (int*)(ws + 39845888);

  detect_mask_kernel<<<1, 256, 0, stream>>>(mask, flag);
  pack_mask_kernel<<<4096, 256, 0, stream>>>(mask, flag, mb16);
  prep_weights_kernel<<<8192, 256, 0, stream>>>(Wq, Wk, Wv, Wo, WT, WoT);
  gemm_proj_kernel<<<dim3(64,4,3), 256, 0, stream>>>(q, k, v, WT, Qp, Kp, Vt);
  attn_kernel<<<1024, 256, 0, stream>>>(Qp, Kp, Vt, (const u32*)mb16, Z);
  gemm_out_kernel<<<dim3(64,8), 256, 0, stream>>>(Z, WoT, out);
  (void)in_sizes; (void)n_in; (void)out_size; (void)ws_size;
}